// Round 3
// baseline (409.566 us; speedup 1.0000x reference)
//
#include <hip/hip_runtime.h>
#include <hip/hip_bf16.h>

#define DIN 256
#define DHID 128
#define NCLS 47
#define BSHIFT 9                 // bucket = dst >> 9  (512 nodes/bucket)
#define BNODES 512
#define NPART 256                // edge partitions (one histogram each)
#define BCAPS 9216               // per-bucket LDS stage cap (lambda 8192 + 11 sigma)
#define CHUNKE 6400              // per-partition LDS stage cap (chunk = 6250)

typedef __attribute__((ext_vector_type(8))) short short8;   // 8 bf16 (4 VGPRs)
typedef __attribute__((ext_vector_type(4))) float f32x4;

__device__ __forceinline__ short f2bf(float f) {
    __bf16 b = (__bf16)f;                 // RNE convert
    return __builtin_bit_cast(short, b);
}
__device__ __forceinline__ float bfu(unsigned int u) {   // low 16 bits = bf16
    return __uint_as_float(u << 16);
}
__device__ __forceinline__ float bfh(unsigned int u) {   // high 16 bits = bf16
    return __uint_as_float(u & 0xffff0000u);
}
__device__ __forceinline__ unsigned int pack2(float lo, float hi) {
    return (unsigned int)(unsigned short)f2bf(lo)
         | ((unsigned int)(unsigned short)f2bf(hi) << 16);
}
// a[j] += row[j] (8 bf16 in one uint4)
__device__ __forceinline__ void add8(float* a, uint4 v) {
    a[0] += bfu(v.x); a[1] += bfh(v.x);
    a[2] += bfu(v.y); a[3] += bfh(v.y);
    a[4] += bfu(v.z); a[5] += bfh(v.z);
    a[6] += bfu(v.w); a[7] += bfh(v.w);
}
// a[j] += d * row[j]
__device__ __forceinline__ void fma8(float* a, uint4 v, float d) {
    a[0] += d * bfu(v.x); a[1] += d * bfh(v.x);
    a[2] += d * bfu(v.y); a[3] += d * bfh(v.y);
    a[4] += d * bfu(v.z); a[5] += d * bfh(v.z);
    a[6] += d * bfu(v.w); a[7] += d * bfh(v.w);
}

// ===== L1: weight swizzles + per-partition histogram (disjoint blocks) =====
// ghist layout TRANSPOSED: ghist[bucket * NPART + part] (coalesced scan later)
__global__ __launch_bounds__(256) void k_prep_hist(const float* __restrict__ W1,
                                                   const float* __restrict__ W2,
                                                   short* __restrict__ W1s,
                                                   short* __restrict__ W2s,
                                                   const int* __restrict__ dst,
                                                   int* __restrict__ ghist,
                                                   int E, int NB, int chunk) {
    __shared__ int lh[256];
    int blk = blockIdx.x, t = threadIdx.x;
    if (blk < 16) {                      // W1 -> B-fragment swizzle
        int tid = blk * 256 + t;         // 0..4095
        int frag = tid >> 6, lane = tid & 63;
        int kt = frag >> 3, nt = frag & 7;
        int quad = lane >> 4, col = lane & 15;
        #pragma unroll
        for (int j = 0; j < 8; ++j) {
            int k = kt * 32 + quad * 8 + j;
            W1s[(size_t)tid * 8 + j] = f2bf(W1[k * DHID + nt * 16 + col]);
        }
    } else if (blk < 20) {               // W2 -> B-fragment swizzle (pad N to 64)
        int tid = (blk - 16) * 256 + t;  // 0..1023
        int frag = tid >> 6, lane = tid & 63;
        int kt = frag >> 2, nt = frag & 3;
        int quad = lane >> 4, col = lane & 15;
        int c = nt * 16 + col;
        #pragma unroll
        for (int j = 0; j < 8; ++j) {
            int k = kt * 32 + quad * 8 + j;
            float v = (c < NCLS) ? W2[k * NCLS + c] : 0.0f;
            W2s[(size_t)tid * 8 + j] = f2bf(v);
        }
    } else {                             // per-partition bucket histogram
        int p = blk - 20;
        for (int i = t; i < NB; i += 256) lh[i] = 0;
        __syncthreads();
        int lo = p * chunk, hi = min(E, lo + chunk);
        for (int i = lo + t; i < hi; i += 256)
            atomicAdd(&lh[dst[i] >> BSHIFT], 1);
        __syncthreads();
        for (int i = t; i < NB; i += 256) ghist[(size_t)i * NPART + p] = lh[i];
    }
}

// ===== L2: scatter (with inline colscan) PARALLEL gemm1 (disjoint blocks) ==
// scatter: packed = src(17b) | (dst & 511) << 17, dest-ordered global writes.
// gemm1: hb = bf16(x @ W1) — independent of the CSR chain, hides under it.
__global__ __launch_bounds__(256) void k_scatter_gemm1(const int* __restrict__ src,
                                                       const int* __restrict__ dst,
                                                       const int* __restrict__ ghist,
                                                       int* __restrict__ btot,
                                                       unsigned int* __restrict__ bbuf,
                                                       int E, int NB, int chunk,
                                                       const float* __restrict__ x,
                                                       const short* __restrict__ W1s,
                                                       short* __restrict__ hb, int n) {
    __shared__ __align__(16) char smem[65536];
    int blk = blockIdx.x, t = threadIdx.x;

    if (blk < NPART) {
        // ---------------- scatter path --------------------------------
        unsigned int* stage = (unsigned int*)smem;        // 25600 B
        int* sdest = (int*)(smem + 25600);                // 25600 B
        int* lcur  = (int*)(smem + 51200);                //  1024 B
        int* gdst  = (int*)(smem + 52224);                //  1024 B
        int* wsum  = (int*)(smem + 53248);                //    16 B

        // inline column scan over partitions (transposed ghist: contiguous)
        int tot = 0, pref = 0, mine = 0;
        if (t < NB) {
            const int* gp = ghist + (size_t)t * NPART;
            mine = gp[blk];
            #pragma unroll 8
            for (int p = 0; p < NPART; ++p) {
                int v = gp[p];
                tot += v;
                pref += (p < blk) ? v : 0;
            }
        }
        if (blk == 0 && t < NB) btot[t] = tot;   // for k_bsort's scan

        int lane = t & 63, w = t >> 6;
        // scan 1: bucket base = exclusive scan over buckets of tot
        int incl = tot;
        #pragma unroll
        for (int off = 1; off < 64; off <<= 1) {
            int u = __shfl_up(incl, off, 64);
            if (lane >= off) incl += u;
        }
        if (lane == 63) wsum[w] = incl;
        __syncthreads();
        int wadd = 0;
        for (int i = 0; i < w; ++i) wadd += wsum[i];
        int bbase = wadd + incl - tot;
        __syncthreads();                         // protect wsum before reuse
        // scan 2: ex = exclusive scan over buckets of this block's counts
        incl = mine;
        #pragma unroll
        for (int off = 1; off < 64; off <<= 1) {
            int u = __shfl_up(incl, off, 64);
            if (lane >= off) incl += u;
        }
        if (lane == 63) wsum[w] = incl;
        __syncthreads();
        wadd = 0;
        for (int i = 0; i < w; ++i) wadd += wsum[i];
        int ex = wadd + incl - mine;

        lcur[t] = ex;
        gdst[t] = bbase + pref - ex;             // sdest = gdst[b] + slot
        __syncthreads();

        int lo = blk * chunk, hi = min(E, lo + chunk), cnt = hi - lo;
        for (int i = lo + t; i < hi; i += 256) {
            int d = dst[i];
            int b = d >> BSHIFT;
            int slot = atomicAdd(&lcur[b], 1);
            stage[slot] = (unsigned int)src[i] | ((unsigned int)(d & (BNODES - 1)) << 17);
            sdest[slot] = gdst[b] + slot;
        }
        __syncthreads();
        for (int i = t; i < cnt; i += 256)       // consecutive i -> consecutive dest
            bbuf[sdest[i]] = stage[i];
    } else {
        // ---------------- gemm1 path: hb = bf16(x @ W1) ----------------
        short* lw = (short*)smem;     // 64 KB: full swizzled W1
        {
            const uint4* g = (const uint4*)W1s;
            uint4* l = (uint4*)lw;
            for (int i = t; i < 4096; i += 256) l[i] = g[i];
        }
        __syncthreads();

        int bid = blk - NPART;
        int wave = t >> 6, lane = t & 63;
        int quad = lane >> 4, lrow = lane & 15;
        long long rowbase = (long long)bid * 128 + wave * 32;

        f32x4 acc[2][8];
        #pragma unroll
        for (int rt = 0; rt < 2; ++rt)
            #pragma unroll
            for (int nt = 0; nt < 8; ++nt) acc[rt][nt] = (f32x4){0.f, 0.f, 0.f, 0.f};

        const short8* lf = (const short8*)lw;

        #pragma unroll
        for (int kt = 0; kt < 8; ++kt) {
            int k0 = kt * 32 + quad * 8;
            short8 a[2];
            #pragma unroll
            for (int rt = 0; rt < 2; ++rt) {
                long long row = rowbase + rt * 16 + lrow;
                float4 v0 = {0.f,0.f,0.f,0.f}, v1 = {0.f,0.f,0.f,0.f};
                if (row < n) {
                    const float* xp = x + row * DIN + k0;
                    v0 = *(const float4*)xp;
                    v1 = *(const float4*)(xp + 4);
                }
                short8 av;
                av[0] = f2bf(v0.x); av[1] = f2bf(v0.y); av[2] = f2bf(v0.z); av[3] = f2bf(v0.w);
                av[4] = f2bf(v1.x); av[5] = f2bf(v1.y); av[6] = f2bf(v1.z); av[7] = f2bf(v1.w);
                a[rt] = av;
            }
            #pragma unroll
            for (int nt = 0; nt < 8; ++nt) {
                short8 b = lf[(kt * 8 + nt) * 64 + lane];
                acc[0][nt] = __builtin_amdgcn_mfma_f32_16x16x32_bf16(a[0], b, acc[0][nt], 0, 0, 0);
                acc[1][nt] = __builtin_amdgcn_mfma_f32_16x16x32_bf16(a[1], b, acc[1][nt], 0, 0, 0);
            }
        }
        #pragma unroll
        for (int rt = 0; rt < 2; ++rt)
            #pragma unroll
            for (int nt = 0; nt < 8; ++nt)
                #pragma unroll
                for (int r = 0; r < 4; ++r) {
                    long long row = rowbase + rt * 16 + quad * 4 + r;
                    if (row < n) hb[row * DHID + nt * 16 + lrow] = f2bf(acc[rt][nt][r]);
                }
    }
}

// 256-thread exclusive scan of btot -> lbase[0..255]; ends synced
__device__ __forceinline__ void scan_btot(const int* __restrict__ btot, int NB,
                                          int* lbase, int* wsum) {
    int t = threadIdx.x;
    int v = (t < NB) ? btot[t] : 0;
    int incl = v;
    int lane = t & 63, w = t >> 6;
    #pragma unroll
    for (int off = 1; off < 64; off <<= 1) {
        int u = __shfl_up(incl, off, 64);
        if (lane >= off) incl += u;
    }
    if (lane == 63) wsum[w] = incl;
    __syncthreads();
    int wadd = 0;
    for (int i = 0; i < w; ++i) wadd += wsum[i];
    lbase[t] = wadd + incl - v;   // exclusive
    __syncthreads();
}

// ===== L3: per-bucket counting sort (in place) + degree/dinv ===============
__global__ __launch_bounds__(256) void k_bsort(const int* __restrict__ btot,
                                               unsigned int* __restrict__ bbuf,
                                               int* __restrict__ degi,
                                               int* __restrict__ beg,
                                               float* __restrict__ dinv, int n, int NB) {
    __shared__ unsigned int stage[BCAPS];
    __shared__ int hist[BNODES];
    __shared__ int cur[BNODES];
    __shared__ int lbase[256];
    __shared__ int wsum[4];

    int b = blockIdx.x, t = threadIdx.x;
    scan_btot(btot, NB, lbase, wsum);
    int cnt = min(btot[b], BCAPS);
    int gbase = lbase[b];
    int node0 = b << BSHIFT;

    if (t < 128) { ((int2*)hist)[t] = (int2){0, 0}; ((int2*)hist)[t + 128] = (int2){0, 0}; }
    __syncthreads();

    for (int i = t; i < cnt; i += 256) {
        unsigned int p = bbuf[gbase + i];
        stage[i] = p;
        atomicAdd(&hist[p >> 17], 1);
    }
    __syncthreads();

    // exclusive scan of 512 counters: thread t owns pair (2t, 2t+1)
    int v0 = hist[2 * t], v1 = hist[2 * t + 1];
    int s = v0 + v1;
    int incl = s;
    int lane = t & 63, w = t >> 6;
    #pragma unroll
    for (int off = 1; off < 64; off <<= 1) {
        int u = __shfl_up(incl, off, 64);
        if (lane >= off) incl += u;
    }
    if (lane == 63) wsum[w] = incl;
    __syncthreads();
    int wadd = 0;
    for (int i = 0; i < w; ++i) wadd += wsum[i];
    int ex = wadd + incl - s;
    cur[2 * t] = ex;
    cur[2 * t + 1] = ex + v0;
    int nodeA = node0 + 2 * t, nodeB = node0 + 2 * t + 1;
    if (nodeA < n) {
        degi[nodeA] = v0;
        beg[nodeA]  = gbase + ex;
        dinv[nodeA] = rsqrtf((float)(v0 + 1));
    }
    if (nodeB < n) {
        degi[nodeB] = v1;
        beg[nodeB]  = gbase + ex + v0;
        dinv[nodeB] = rsqrtf((float)(v1 + 1));
    }
    __syncthreads();

    for (int i = t; i < cnt; i += 256) {
        unsigned int p = stage[i];
        int slot = atomicAdd(&cur[p >> 17], 1);
        bbuf[gbase + slot] = p & 0x1FFFFu;
    }
}

// ===== L4: gather1 (round-1 interleave) + FUSED gemm2 ======================
// 1024 threads = 16 waves = 16 nodes/block. Per wave: 4 edge-groups x 16
// dim-lanes gather one node's h1 row; stage bf16 rows in LDS; waves 0..3
// run the 16x64 MFMA (h1 @ W2pad), writing dinv-prescaled h2b directly.
// Kills the gemm2 launch and the 51 MB h1b round-trip.
__global__ __launch_bounds__(1024) void k_g1g2(const int* __restrict__ beg,
                          const int* __restrict__ degi,
                          const int* __restrict__ ssrc, const float* __restrict__ dinv,
                          const uint4* __restrict__ hb4, const float* __restrict__ b1,
                          const short* __restrict__ W2s,
                          short* __restrict__ h2b, int n) {
    __shared__ short lw[8192];          // 16 KB swizzled W2
    __shared__ short h1s[16 * 136];     // 16 rows, stride 136 (=272B, 16B-aligned,
                                        //  breaks the 256B same-bank pattern)
    ((uint4*)lw)[threadIdx.x & 1023] = ((const uint4*)W2s)[threadIdx.x & 1023];

    int wv = threadIdx.x >> 6;          // wave = node
    int t  = threadIdx.x & 63;
    int grp = t >> 4, sub = t & 15;     // 4 edge-groups x 16 dim-lanes
    int node = blockIdx.x * 16 + wv;
    bool alive = node < n;
    int cnt = alive ? degi[node] : 0;
    int bg  = alive ? beg[node]  : 0;

    float a[8] = {0.f,0.f,0.f,0.f,0.f,0.f,0.f,0.f};
    int k = 0;
    for (; k + 16 <= cnt; k += 16) {    // group grp owns edges k+grp*4..+3
        int s[4];
        #pragma unroll
        for (int q = 0; q < 4; ++q) s[q] = ssrc[bg + k + grp * 4 + q];
        float dv[4]; uint4 v[4];
        #pragma unroll
        for (int q = 0; q < 4; ++q) { dv[q] = dinv[s[q]]; v[q] = hb4[(size_t)s[q] * 16 + sub]; }
        #pragma unroll
        for (int q = 0; q < 4; ++q) fma8(a, v[q], dv[q]);
    }
    for (; k < cnt; k += 4) {           // predicated tail quad
        int idx = k + grp;
        if (idx < cnt) {
            int s = ssrc[bg + idx];
            fma8(a, hb4[(size_t)s * 16 + sub], dinv[s]);
        }
    }
    #pragma unroll
    for (int j = 0; j < 8; ++j) {       // combine the 4 edge-groups
        a[j] += __shfl_xor(a[j], 16);
        a[j] += __shfl_xor(a[j], 32);
    }

    if (grp == 0) {                     // epilogue + stage h1 row to LDS
        uint4 o = {0u, 0u, 0u, 0u};
        if (alive) {
            uint4 sv = hb4[(size_t)node * 16 + sub];
            float di = dinv[node], dd = di * di;
            float4 bA = ((const float4*)b1)[sub * 2];
            float4 bB = ((const float4*)b1)[sub * 2 + 1];
            float v0 = fmaxf(di * a[0] + dd * bfu(sv.x) + bA.x, 0.f);
            float v1 = fmaxf(di * a[1] + dd * bfh(sv.x) + bA.y, 0.f);
            float v2 = fmaxf(di * a[2] + dd * bfu(sv.y) + bA.z, 0.f);
            float v3 = fmaxf(di * a[3] + dd * bfh(sv.y) + bA.w, 0.f);
            float v4 = fmaxf(di * a[4] + dd * bfu(sv.z) + bB.x, 0.f);
            float v5 = fmaxf(di * a[5] + dd * bfh(sv.z) + bB.y, 0.f);
            float v6 = fmaxf(di * a[6] + dd * bfu(sv.w) + bB.z, 0.f);
            float v7 = fmaxf(di * a[7] + dd * bfh(sv.w) + bB.w, 0.f);
            o.x = pack2(v0, v1);
            o.y = pack2(v2, v3);
            o.z = pack2(v4, v5);
            o.w = pack2(v6, v7);
        }
        *(uint4*)(h1s + wv * 136 + sub * 8) = o;
    }
    __syncthreads();

    if (wv < 4) {                       // gemm2: wave wv owns col tile nt=wv
        int quad = t >> 4, lrow = t & 15;
        f32x4 acc = (f32x4){0.f, 0.f, 0.f, 0.f};
        const short8* lf = (const short8*)lw;
        #pragma unroll
        for (int kt = 0; kt < 4; ++kt) {
            short8 aa = *(const short8*)(h1s + lrow * 136 + kt * 32 + quad * 8);
            acc = __builtin_amdgcn_mfma_f32_16x16x32_bf16(aa, lf[(kt * 4 + wv) * 64 + t], acc, 0, 0, 0);
        }
        #pragma unroll
        for (int r = 0; r < 4; ++r) {   // prescale by dinv[row] for gather2
            int nodeo = blockIdx.x * 16 + quad * 4 + r;
            if (nodeo < n) h2b[(size_t)nodeo * 64 + wv * 16 + lrow] = f2bf(acc[r] * dinv[nodeo]);
        }
    }
}

// ===== L5: gather2 (round-1 interleave, prescaled h2b => no dinv loads) ====
__global__ __launch_bounds__(256) void k_gather2(const int* __restrict__ beg,
                          const int* __restrict__ degi,
                          const int* __restrict__ ssrc, const float* __restrict__ dinv,
                          const uint4* __restrict__ h2b4, const float* __restrict__ b2,
                          float* __restrict__ out, int n) {
    int node = blockIdx.x * 4 + (threadIdx.x >> 6);
    int t = threadIdx.x & 63;
    if (node >= n) return;
    int cnt = degi[node];
    int bg  = beg[node];
    int grp = t >> 3, sub = t & 7;            // 8 edge-groups x 8 dim-lanes

    float a[8] = {0.f,0.f,0.f,0.f,0.f,0.f,0.f,0.f};
    int k = 0;
    for (; k + 16 <= cnt; k += 16) {          // 16 edges: 2 x 1KB wave-loads
        int s0 = ssrc[bg + k + grp], s1 = ssrc[bg + k + 8 + grp];
        uint4 v0 = h2b4[(size_t)s0 * 8 + sub];
        uint4 v1 = h2b4[(size_t)s1 * 8 + sub];
        add8(a, v0); add8(a, v1);
    }
    for (; k < cnt; k += 8) {                 // predicated tail octet
        int idx = k + grp;
        if (idx < cnt) {
            int s = ssrc[bg + idx];
            add8(a, h2b4[(size_t)s * 8 + sub]);
        }
    }
    if (grp == 0) add8(a, h2b4[(size_t)node * 8 + sub]);   // self (prescaled)

    #pragma unroll
    for (int j = 0; j < 8; ++j) {             // combine the 8 edge-groups
        a[j] += __shfl_xor(a[j], 8);
        a[j] += __shfl_xor(a[j], 16);
        a[j] += __shfl_xor(a[j], 32);
    }

    if (grp == 0) {
        float di = dinv[node];
        #pragma unroll
        for (int j = 0; j < 8; ++j) {
            int c = sub * 8 + j;
            if (c < NCLS) out[(size_t)node * NCLS + c] = di * a[j] + b2[c];
        }
    }
}

// ===========================================================================
extern "C" void kernel_launch(void* const* d_in, const int* in_sizes, int n_in,
                              void* d_out, int out_size, void* d_ws, size_t ws_size,
                              hipStream_t stream) {
    const float* x  = (const float*)d_in[0];
    const int*   ei = (const int*)d_in[1];
    const float* W1 = (const float*)d_in[2];
    const float* b1 = (const float*)d_in[3];
    const float* W2 = (const float*)d_in[4];
    const float* b2 = (const float*)d_in[5];

    const int n = in_sizes[0] / DIN;   // 100000
    const int E = in_sizes[1] / 2;     // 1600000
    const int* src = ei;
    const int* dst = ei + E;
    float* out = (float*)d_out;

    const int NB = (n + BNODES - 1) >> BSHIFT;   // 196 buckets
    const int chunk = (E + NPART - 1) / NPART;   // 6250

    // workspace layout (~46 MB)
    char* w = (char*)d_ws;
    int*   ghist = (int*)w;                    w += (size_t)NB * NPART * 4;   // 200 KB (transposed)
    int*   btot  = (int*)w;                    w += ((size_t)NB * 4 + 15) & ~15ull;
    int*   degi  = (int*)w;                    w += (size_t)n * 4;
    int*   beg   = (int*)w;                    w += (size_t)n * 4;
    float* dinv  = (float*)w;                  w += (size_t)n * 4;
    short* W1s   = (short*)w;                  w += (size_t)32768 * 2;        // 64 KB
    short* W2s   = (short*)w;                  w += (size_t)8192 * 2;         // 16 KB
    unsigned int* bbuf = (unsigned int*)w;     w += (size_t)E * 4;            // 6.4 MB -> ssrc
    short* hb    = (short*)w;                  w += (size_t)n * DHID * 2;     // bf16 x@W1
    short* h2b   = (short*)w;                  w += (size_t)n * 64 * 2;       // bf16 (h1@W2)*dinv

    // L1: weight swizzles + histogram
    k_prep_hist<<<20 + NPART, 256, 0, stream>>>(W1, W2, W1s, W2s, dst, ghist, E, NB, chunk);
    // L2: scatter (CSR build) || gemm1 (independent -> hidden)
    k_scatter_gemm1<<<NPART + (n + 127) / 128, 256, 0, stream>>>(src, dst, ghist, btot, bbuf,
                                                                 E, NB, chunk, x, W1s, hb, n);
    // L3: per-bucket counting sort + degrees/dinv
    k_bsort<<<NB, 256, 0, stream>>>(btot, bbuf, degi, beg, dinv, n, NB);
    // L4: gather1 + fused gemm2 (writes prescaled h2b)
    k_g1g2<<<(n + 15) / 16, 1024, 0, stream>>>(beg, degi, (const int*)bbuf, dinv,
                                               (const uint4*)hb, b1, W2s, h2b, n);
    // L5: gather2 (fused bias+self)
    k_gather2<<<(n + 3) / 4, 256, 0, stream>>>(beg, degi, (const int*)bbuf, dinv,
                                               (const uint4*)h2b, b2, out, n);
}

// Round 4
// 402.637 us; speedup vs baseline: 1.0172x; 1.0172x over previous
//
#include <hip/hip_runtime.h>
#include <hip/hip_bf16.h>

#define DIN 256
#define DHID 128
#define NCLS 47
#define BSHIFT 9                 // bucket = dst >> 9  (512 nodes/bucket)
#define BNODES 512
#define NPART 256                // edge partitions (one histogram each)
#define BCAPS 9216               // per-bucket LDS stage cap (lambda 8192 + 11 sigma)
#define CHUNKE 6400              // per-partition LDS stage cap (chunk = 6250)

typedef __attribute__((ext_vector_type(8))) short short8;   // 8 bf16 (4 VGPRs)
typedef __attribute__((ext_vector_type(4))) float f32x4;

__device__ __forceinline__ short f2bf(float f) {
    __bf16 b = (__bf16)f;                 // RNE convert
    return __builtin_bit_cast(short, b);
}
__device__ __forceinline__ float bfu(unsigned int u) {   // low 16 bits = bf16
    return __uint_as_float(u << 16);
}
__device__ __forceinline__ float bfh(unsigned int u) {   // high 16 bits = bf16
    return __uint_as_float(u & 0xffff0000u);
}
__device__ __forceinline__ unsigned int pack2(float lo, float hi) {
    return (unsigned int)(unsigned short)f2bf(lo)
         | ((unsigned int)(unsigned short)f2bf(hi) << 16);
}
// a[j] += row[j] (8 bf16 in one uint4)
__device__ __forceinline__ void add8(float* a, uint4 v) {
    a[0] += bfu(v.x); a[1] += bfh(v.x);
    a[2] += bfu(v.y); a[3] += bfh(v.y);
    a[4] += bfu(v.z); a[5] += bfh(v.z);
    a[6] += bfu(v.w); a[7] += bfh(v.w);
}
// a[j] += d * row[j]
__device__ __forceinline__ void fma8(float* a, uint4 v, float d) {
    a[0] += d * bfu(v.x); a[1] += d * bfh(v.x);
    a[2] += d * bfu(v.y); a[3] += d * bfh(v.y);
    a[4] += d * bfu(v.z); a[5] += d * bfh(v.z);
    a[6] += d * bfu(v.w); a[7] += d * bfh(v.w);
}

// ===== L1: weight swizzles + per-partition histogram (disjoint blocks) =====
// ghist layout TRANSPOSED: ghist[bucket * NPART + part] (coalesced scan later)
__global__ __launch_bounds__(256) void k_prep_hist(const float* __restrict__ W1,
                                                   const float* __restrict__ W2,
                                                   short* __restrict__ W1s,
                                                   short* __restrict__ W2s,
                                                   const int* __restrict__ dst,
                                                   int* __restrict__ ghist,
                                                   int E, int NB, int chunk) {
    __shared__ int lh[256];
    int blk = blockIdx.x, t = threadIdx.x;
    if (blk < 16) {                      // W1 -> B-fragment swizzle
        int tid = blk * 256 + t;         // 0..4095
        int frag = tid >> 6, lane = tid & 63;
        int kt = frag >> 3, nt = frag & 7;
        int quad = lane >> 4, col = lane & 15;
        #pragma unroll
        for (int j = 0; j < 8; ++j) {
            int k = kt * 32 + quad * 8 + j;
            W1s[(size_t)tid * 8 + j] = f2bf(W1[k * DHID + nt * 16 + col]);
        }
    } else if (blk < 20) {               // W2 -> B-fragment swizzle (pad N to 64)
        int tid = (blk - 16) * 256 + t;  // 0..1023
        int frag = tid >> 6, lane = tid & 63;
        int kt = frag >> 2, nt = frag & 3;
        int quad = lane >> 4, col = lane & 15;
        int c = nt * 16 + col;
        #pragma unroll
        for (int j = 0; j < 8; ++j) {
            int k = kt * 32 + quad * 8 + j;
            float v = (c < NCLS) ? W2[k * NCLS + c] : 0.0f;
            W2s[(size_t)tid * 8 + j] = f2bf(v);
        }
    } else {                             // per-partition bucket histogram
        int p = blk - 20;
        for (int i = t; i < NB; i += 256) lh[i] = 0;
        __syncthreads();
        int lo = p * chunk, hi = min(E, lo + chunk);
        for (int i = lo + t; i < hi; i += 256)
            atomicAdd(&lh[dst[i] >> BSHIFT], 1);
        __syncthreads();
        for (int i = t; i < NB; i += 256) ghist[(size_t)i * NPART + p] = lh[i];
    }
}

// ===== L2: scatter (with inline colscan) PARALLEL gemm1 (disjoint blocks) ==
// scatter: packed = src(17b) | (dst & 511) << 17, dest-ordered global writes.
// gemm1: hb = bf16(x @ W1) — independent of the CSR chain, hides under it.
__global__ __launch_bounds__(256) void k_scatter_gemm1(const int* __restrict__ src,
                                                       const int* __restrict__ dst,
                                                       const int* __restrict__ ghist,
                                                       int* __restrict__ btot,
                                                       unsigned int* __restrict__ bbuf,
                                                       int E, int NB, int chunk,
                                                       const float* __restrict__ x,
                                                       const short* __restrict__ W1s,
                                                       short* __restrict__ hb, int n) {
    __shared__ __align__(16) char smem[65536];
    int blk = blockIdx.x, t = threadIdx.x;

    if (blk < NPART) {
        // ---------------- scatter path --------------------------------
        unsigned int* stage = (unsigned int*)smem;        // 25600 B
        int* sdest = (int*)(smem + 25600);                // 25600 B
        int* lcur  = (int*)(smem + 51200);                //  1024 B
        int* gdst  = (int*)(smem + 52224);                //  1024 B
        int* wsum  = (int*)(smem + 53248);                //    16 B

        // inline column scan over partitions (transposed ghist: contiguous)
        int tot = 0, pref = 0, mine = 0;
        if (t < NB) {
            const int* gp = ghist + (size_t)t * NPART;
            mine = gp[blk];
            #pragma unroll 8
            for (int p = 0; p < NPART; ++p) {
                int v = gp[p];
                tot += v;
                pref += (p < blk) ? v : 0;
            }
        }
        if (blk == 0 && t < NB) btot[t] = tot;   // for k_bsort's scan

        int lane = t & 63, w = t >> 6;
        // scan 1: bucket base = exclusive scan over buckets of tot
        int incl = tot;
        #pragma unroll
        for (int off = 1; off < 64; off <<= 1) {
            int u = __shfl_up(incl, off, 64);
            if (lane >= off) incl += u;
        }
        if (lane == 63) wsum[w] = incl;
        __syncthreads();
        int wadd = 0;
        for (int i = 0; i < w; ++i) wadd += wsum[i];
        int bbase = wadd + incl - tot;
        __syncthreads();                         // protect wsum before reuse
        // scan 2: ex = exclusive scan over buckets of this block's counts
        incl = mine;
        #pragma unroll
        for (int off = 1; off < 64; off <<= 1) {
            int u = __shfl_up(incl, off, 64);
            if (lane >= off) incl += u;
        }
        if (lane == 63) wsum[w] = incl;
        __syncthreads();
        wadd = 0;
        for (int i = 0; i < w; ++i) wadd += wsum[i];
        int ex = wadd + incl - mine;

        lcur[t] = ex;
        gdst[t] = bbase + pref - ex;             // sdest = gdst[b] + slot
        __syncthreads();

        int lo = blk * chunk, hi = min(E, lo + chunk), cnt = hi - lo;
        for (int i = lo + t; i < hi; i += 256) {
            int d = dst[i];
            int b = d >> BSHIFT;
            int slot = atomicAdd(&lcur[b], 1);
            stage[slot] = (unsigned int)src[i] | ((unsigned int)(d & (BNODES - 1)) << 17);
            sdest[slot] = gdst[b] + slot;
        }
        __syncthreads();
        for (int i = t; i < cnt; i += 256)       // consecutive i -> consecutive dest
            bbuf[sdest[i]] = stage[i];
    } else {
        // ---------------- gemm1 path: hb = bf16(x @ W1) ----------------
        short* lw = (short*)smem;     // 64 KB: full swizzled W1
        {
            const uint4* g = (const uint4*)W1s;
            uint4* l = (uint4*)lw;
            for (int i = t; i < 4096; i += 256) l[i] = g[i];
        }
        __syncthreads();

        int bid = blk - NPART;
        int wave = t >> 6, lane = t & 63;
        int quad = lane >> 4, lrow = lane & 15;
        long long rowbase = (long long)bid * 128 + wave * 32;

        f32x4 acc[2][8];
        #pragma unroll
        for (int rt = 0; rt < 2; ++rt)
            #pragma unroll
            for (int nt = 0; nt < 8; ++nt) acc[rt][nt] = (f32x4){0.f, 0.f, 0.f, 0.f};

        const short8* lf = (const short8*)lw;

        #pragma unroll
        for (int kt = 0; kt < 8; ++kt) {
            int k0 = kt * 32 + quad * 8;
            short8 a[2];
            #pragma unroll
            for (int rt = 0; rt < 2; ++rt) {
                long long row = rowbase + rt * 16 + lrow;
                float4 v0 = {0.f,0.f,0.f,0.f}, v1 = {0.f,0.f,0.f,0.f};
                if (row < n) {
                    const float* xp = x + row * DIN + k0;
                    v0 = *(const float4*)xp;
                    v1 = *(const float4*)(xp + 4);
                }
                short8 av;
                av[0] = f2bf(v0.x); av[1] = f2bf(v0.y); av[2] = f2bf(v0.z); av[3] = f2bf(v0.w);
                av[4] = f2bf(v1.x); av[5] = f2bf(v1.y); av[6] = f2bf(v1.z); av[7] = f2bf(v1.w);
                a[rt] = av;
            }
            #pragma unroll
            for (int nt = 0; nt < 8; ++nt) {
                short8 b = lf[(kt * 8 + nt) * 64 + lane];
                acc[0][nt] = __builtin_amdgcn_mfma_f32_16x16x32_bf16(a[0], b, acc[0][nt], 0, 0, 0);
                acc[1][nt] = __builtin_amdgcn_mfma_f32_16x16x32_bf16(a[1], b, acc[1][nt], 0, 0, 0);
            }
        }
        #pragma unroll
        for (int rt = 0; rt < 2; ++rt)
            #pragma unroll
            for (int nt = 0; nt < 8; ++nt)
                #pragma unroll
                for (int r = 0; r < 4; ++r) {
                    long long row = rowbase + rt * 16 + quad * 4 + r;
                    if (row < n) hb[row * DHID + nt * 16 + lrow] = f2bf(acc[rt][nt][r]);
                }
    }
}

// 256-thread exclusive scan of btot -> lbase[0..255]; ends synced
__device__ __forceinline__ void scan_btot(const int* __restrict__ btot, int NB,
                                          int* lbase, int* wsum) {
    int t = threadIdx.x;
    int v = (t < NB) ? btot[t] : 0;
    int incl = v;
    int lane = t & 63, w = t >> 6;
    #pragma unroll
    for (int off = 1; off < 64; off <<= 1) {
        int u = __shfl_up(incl, off, 64);
        if (lane >= off) incl += u;
    }
    if (lane == 63) wsum[w] = incl;
    __syncthreads();
    int wadd = 0;
    for (int i = 0; i < w; ++i) wadd += wsum[i];
    lbase[t] = wadd + incl - v;   // exclusive
    __syncthreads();
}

// ===== L3: per-bucket counting sort (in place) + degree/dinv ===============
__global__ __launch_bounds__(256) void k_bsort(const int* __restrict__ btot,
                                               unsigned int* __restrict__ bbuf,
                                               int* __restrict__ degi,
                                               int* __restrict__ beg,
                                               float* __restrict__ dinv, int n, int NB) {
    __shared__ unsigned int stage[BCAPS];
    __shared__ int hist[BNODES];
    __shared__ int cur[BNODES];
    __shared__ int lbase[256];
    __shared__ int wsum[4];

    int b = blockIdx.x, t = threadIdx.x;
    scan_btot(btot, NB, lbase, wsum);
    int cnt = min(btot[b], BCAPS);
    int gbase = lbase[b];
    int node0 = b << BSHIFT;

    if (t < 128) { ((int2*)hist)[t] = (int2){0, 0}; ((int2*)hist)[t + 128] = (int2){0, 0}; }
    __syncthreads();

    for (int i = t; i < cnt; i += 256) {
        unsigned int p = bbuf[gbase + i];
        stage[i] = p;
        atomicAdd(&hist[p >> 17], 1);
    }
    __syncthreads();

    // exclusive scan of 512 counters: thread t owns pair (2t, 2t+1)
    int v0 = hist[2 * t], v1 = hist[2 * t + 1];
    int s = v0 + v1;
    int incl = s;
    int lane = t & 63, w = t >> 6;
    #pragma unroll
    for (int off = 1; off < 64; off <<= 1) {
        int u = __shfl_up(incl, off, 64);
        if (lane >= off) incl += u;
    }
    if (lane == 63) wsum[w] = incl;
    __syncthreads();
    int wadd = 0;
    for (int i = 0; i < w; ++i) wadd += wsum[i];
    int ex = wadd + incl - s;
    cur[2 * t] = ex;
    cur[2 * t + 1] = ex + v0;
    int nodeA = node0 + 2 * t, nodeB = node0 + 2 * t + 1;
    if (nodeA < n) {
        degi[nodeA] = v0;
        beg[nodeA]  = gbase + ex;
        dinv[nodeA] = rsqrtf((float)(v0 + 1));
    }
    if (nodeB < n) {
        degi[nodeB] = v1;
        beg[nodeB]  = gbase + ex + v0;
        dinv[nodeB] = rsqrtf((float)(v1 + 1));
    }
    __syncthreads();

    for (int i = t; i < cnt; i += 256) {
        unsigned int p = stage[i];
        int slot = atomicAdd(&cur[p >> 17], 1);
        bbuf[gbase + slot] = p & 0x1FFFFu;
    }
}

// ===== L4: gather1 — proven round-1 interleave, per-edge dinv ==============
// wave = 1 node; 4 edge-groups x 16 dim-lanes; 4 uint4 gathers in flight.
__global__ __launch_bounds__(256) void k_gather1(const int* __restrict__ beg,
                          const int* __restrict__ degi,
                          const int* __restrict__ ssrc, const float* __restrict__ dinv,
                          const uint4* __restrict__ hb4, const float* __restrict__ b1,
                          uint4* __restrict__ h1u4, int n) {
    int node = blockIdx.x * 4 + (threadIdx.x >> 6);
    int t = threadIdx.x & 63;
    if (node >= n) return;
    int cnt = degi[node];
    int bg  = beg[node];
    int grp = t >> 4, sub = t & 15;           // 4 edge-groups x 16 dim-lanes

    float a[8] = {0.f,0.f,0.f,0.f,0.f,0.f,0.f,0.f};
    int k = 0;
    for (; k + 16 <= cnt; k += 16) {          // 16 edges: 4 x 1KB wave-loads
        int s[4];
        #pragma unroll
        for (int q = 0; q < 4; ++q) s[q] = ssrc[bg + k + grp * 4 + q];
        float dv[4]; uint4 v[4];
        #pragma unroll
        for (int q = 0; q < 4; ++q) { dv[q] = dinv[s[q]]; v[q] = hb4[(size_t)s[q] * 16 + sub]; }
        #pragma unroll
        for (int q = 0; q < 4; ++q) fma8(a, v[q], dv[q]);
    }
    for (; k < cnt; k += 4) {                 // predicated tail quad
        int idx = k + grp;
        if (idx < cnt) {
            int s = ssrc[bg + idx];
            fma8(a, hb4[(size_t)s * 16 + sub], dinv[s]);
        }
    }

    #pragma unroll
    for (int j = 0; j < 8; ++j) {             // combine the 4 edge-groups
        a[j] += __shfl_xor(a[j], 16);
        a[j] += __shfl_xor(a[j], 32);
    }

    if (grp == 0) {                           // 16 lanes write the 256B row
        uint4 sv = hb4[(size_t)node * 16 + sub];
        float di = dinv[node], dd = di * di;
        float4 bA = ((const float4*)b1)[sub * 2];
        float4 bB = ((const float4*)b1)[sub * 2 + 1];
        float v0 = fmaxf(di * a[0] + dd * bfu(sv.x) + bA.x, 0.f);
        float v1 = fmaxf(di * a[1] + dd * bfh(sv.x) + bA.y, 0.f);
        float v2 = fmaxf(di * a[2] + dd * bfu(sv.y) + bA.z, 0.f);
        float v3 = fmaxf(di * a[3] + dd * bfh(sv.y) + bA.w, 0.f);
        float v4 = fmaxf(di * a[4] + dd * bfu(sv.z) + bB.x, 0.f);
        float v5 = fmaxf(di * a[5] + dd * bfh(sv.z) + bB.y, 0.f);
        float v6 = fmaxf(di * a[6] + dd * bfu(sv.w) + bB.z, 0.f);
        float v7 = fmaxf(di * a[7] + dd * bfh(sv.w) + bB.w, 0.f);
        uint4 o;
        o.x = pack2(v0, v1);
        o.y = pack2(v2, v3);
        o.z = pack2(v4, v5);
        o.w = pack2(v6, v7);
        h1u4[(size_t)node * 16 + sub] = o;    // 4 consecutive rows/wave = 1KB
    }
}

// ==== L5: gemm2 via MFMA: h2b[n,64] = bf16( (h1b @ W2pad) * dinv[row] ) ====
// prescale by dinv[row] removes the per-edge dinv load in gather2.
__global__ __launch_bounds__(256) void k_gemm2_mfma(const short* __restrict__ h1b,
                                                    const short* __restrict__ W2s,
                                                    const float* __restrict__ dinv,
                                                    short* __restrict__ h2b, int n) {
    __shared__ short lw[8192];  // 16 KB: swizzled padded W2
    {
        const uint4* g = (const uint4*)W2s;
        uint4* l = (uint4*)lw;
        for (int i = threadIdx.x; i < 1024; i += 256) l[i] = g[i];
    }
    __syncthreads();

    int wave = threadIdx.x >> 6, lane = threadIdx.x & 63;
    int quad = lane >> 4, lrow = lane & 15;
    long long row0 = (long long)blockIdx.x * 64 + wave * 16;

    f32x4 acc[4];
    #pragma unroll
    for (int nt = 0; nt < 4; ++nt) acc[nt] = (f32x4){0.f, 0.f, 0.f, 0.f};

    const short8* lf = (const short8*)lw;

    #pragma unroll
    for (int kt = 0; kt < 4; ++kt) {
        long long row = row0 + lrow;
        short8 a = (short8){0,0,0,0,0,0,0,0};
        if (row < n) a = *(const short8*)(h1b + row * DHID + kt * 32 + quad * 8);
        #pragma unroll
        for (int nt = 0; nt < 4; ++nt)
            acc[nt] = __builtin_amdgcn_mfma_f32_16x16x32_bf16(a, lf[(kt * 4 + nt) * 64 + lane], acc[nt], 0, 0, 0);
    }
    float dvv[4];
    #pragma unroll
    for (int r = 0; r < 4; ++r) {
        long long row = row0 + quad * 4 + r;
        dvv[r] = (row < n) ? dinv[row] : 0.f;
    }
    #pragma unroll
    for (int nt = 0; nt < 4; ++nt)
        #pragma unroll
        for (int r = 0; r < 4; ++r) {
            long long row = row0 + quad * 4 + r;
            if (row < n) h2b[row * 64 + nt * 16 + lrow] = f2bf(acc[nt][r] * dvv[r]);
        }
}

// ===== L6: gather2 (prescaled h2b => pure load/add inner loop) =============
__global__ __launch_bounds__(256) void k_gather2(const int* __restrict__ beg,
                          const int* __restrict__ degi,
                          const int* __restrict__ ssrc, const float* __restrict__ dinv,
                          const uint4* __restrict__ h2b4, const float* __restrict__ b2,
                          float* __restrict__ out, int n) {
    int node = blockIdx.x * 4 + (threadIdx.x >> 6);
    int t = threadIdx.x & 63;
    if (node >= n) return;
    int cnt = degi[node];
    int bg  = beg[node];
    int grp = t >> 3, sub = t & 7;            // 8 edge-groups x 8 dim-lanes

    float a[8] = {0.f,0.f,0.f,0.f,0.f,0.f,0.f,0.f};
    int k = 0;
    for (; k + 16 <= cnt; k += 16) {          // 16 edges: 2 x 1KB wave-loads
        int s0 = ssrc[bg + k + grp], s1 = ssrc[bg + k + 8 + grp];
        uint4 v0 = h2b4[(size_t)s0 * 8 + sub];
        uint4 v1 = h2b4[(size_t)s1 * 8 + sub];
        add8(a, v0); add8(a, v1);
    }
    for (; k < cnt; k += 8) {                 // predicated tail octet
        int idx = k + grp;
        if (idx < cnt) {
            int s = ssrc[bg + idx];
            add8(a, h2b4[(size_t)s * 8 + sub]);
        }
    }
    if (grp == 0) add8(a, h2b4[(size_t)node * 8 + sub]);   // self (prescaled)

    #pragma unroll
    for (int j = 0; j < 8; ++j) {             // combine the 8 edge-groups
        a[j] += __shfl_xor(a[j], 8);
        a[j] += __shfl_xor(a[j], 16);
        a[j] += __shfl_xor(a[j], 32);
    }

    if (grp == 0) {
        float di = dinv[node];
        #pragma unroll
        for (int j = 0; j < 8; ++j) {
            int c = sub * 8 + j;
            if (c < NCLS) out[(size_t)node * NCLS + c] = di * a[j] + b2[c];
        }
    }
}

// ===========================================================================
extern "C" void kernel_launch(void* const* d_in, const int* in_sizes, int n_in,
                              void* d_out, int out_size, void* d_ws, size_t ws_size,
                              hipStream_t stream) {
    const float* x  = (const float*)d_in[0];
    const int*   ei = (const int*)d_in[1];
    const float* W1 = (const float*)d_in[2];
    const float* b1 = (const float*)d_in[3];
    const float* W2 = (const float*)d_in[4];
    const float* b2 = (const float*)d_in[5];

    const int n = in_sizes[0] / DIN;   // 100000
    const int E = in_sizes[1] / 2;     // 1600000
    const int* src = ei;
    const int* dst = ei + E;
    float* out = (float*)d_out;

    const int NB = (n + BNODES - 1) >> BSHIFT;   // 196 buckets
    const int chunk = (E + NPART - 1) / NPART;   // 6250

    // workspace layout (~72 MB)
    char* w = (char*)d_ws;
    int*   ghist = (int*)w;                    w += (size_t)NB * NPART * 4;   // 200 KB (transposed)
    int*   btot  = (int*)w;                    w += ((size_t)NB * 4 + 15) & ~15ull;
    int*   degi  = (int*)w;                    w += (size_t)n * 4;
    int*   beg   = (int*)w;                    w += (size_t)n * 4;
    float* dinv  = (float*)w;                  w += (size_t)n * 4;
    short* W1s   = (short*)w;                  w += (size_t)32768 * 2;        // 64 KB
    short* W2s   = (short*)w;                  w += (size_t)8192 * 2;         // 16 KB
    unsigned int* bbuf = (unsigned int*)w;     w += (size_t)E * 4;            // 6.4 MB -> ssrc
    short* hb    = (short*)w;                  w += (size_t)n * DHID * 2;     // bf16 x@W1
    short* h1b   = (short*)w;                  w += (size_t)n * DHID * 2;     // bf16 relu layer1
    short* h2b   = (short*)w;                  w += (size_t)n * 64 * 2;       // bf16 (h1@W2)*dinv

    // L1: weight swizzles + histogram
    k_prep_hist<<<20 + NPART, 256, 0, stream>>>(W1, W2, W1s, W2s, dst, ghist, E, NB, chunk);
    // L2: scatter (CSR build) || gemm1 (independent -> hidden)
    k_scatter_gemm1<<<NPART + (n + 127) / 128, 256, 0, stream>>>(src, dst, ghist, btot, bbuf,
                                                                 E, NB, chunk, x, W1s, hb, n);
    // L3: per-bucket counting sort + degrees/dinv
    k_bsort<<<NB, 256, 0, stream>>>(btot, bbuf, degi, beg, dinv, n, NB);
    // L4: gather1 (fused bias+self+relu, bf16 out)
    k_gather1<<<(n + 3) / 4, 256, 0, stream>>>(beg, degi, (const int*)bbuf, dinv,
                                               (const uint4*)hb, b1,
                                               (uint4*)h1b, n);
    // L5: gemm2 (prescales h2b by dinv[row])
    k_gemm2_mfma<<<(n + 63) / 64, 256, 0, stream>>>(h1b, W2s, dinv, h2b, n);
    // L6: gather2 (fused bias+self)
    k_gather2<<<(n + 3) / 4, 256, 0, stream>>>(beg, degi, (const int*)bbuf, dinv,
                                               (const uint4*)h2b, b2, out, n);
}